// Round 1
// baseline (613.464 us; speedup 1.0000x reference)
//
#include <hip/hip_runtime.h>
#include <hip/hip_bf16.h>

#define C 32
#define LN_EPS 1e-5f
#define P 8            // threads per superpoint in reduce
#define SCAN_BLK 1024

__device__ __forceinline__ unsigned pack_bf16x2(float a, float b) {
    __hip_bfloat162 bb = __float22bfloat162_rn(make_float2(a, b));
    return *reinterpret_cast<unsigned*>(&bb);
}

// ---------- k0: histogram of sp_ids ------------------------------------------
__global__ __launch_bounds__(256) void k0_hist(
    const int* __restrict__ sp_ids, int* __restrict__ count, int n)
{
    int p = blockIdx.x * 256 + threadIdx.x;
    if (p < n) atomicAdd(&count[sp_ids[p]], 1);
}

// ---------- K2a/b/c: exclusive scan of counts --------------------------------
__global__ __launch_bounds__(SCAN_BLK) void k2a_scan_block(
    const int* __restrict__ count, int* __restrict__ off,
    int* __restrict__ bsum, int S)
{
    __shared__ int lds[SCAN_BLK];
    int t = threadIdx.x;
    int i = blockIdx.x * SCAN_BLK + t;
    int v = (i < S) ? count[i] : 0;
    lds[t] = v;
    __syncthreads();
    for (int d = 1; d < SCAN_BLK; d <<= 1) {
        int add = (t >= d) ? lds[t - d] : 0;
        __syncthreads();
        lds[t] += add;
        __syncthreads();
    }
    int incl = lds[t];
    if (i < S) off[i] = incl - v;
    if (t == SCAN_BLK - 1) bsum[blockIdx.x] = incl;
}

__global__ __launch_bounds__(64) void k2b_scan_bsums(int* __restrict__ bsum, int nb)
{
    int lane = threadIdx.x;
    int v = (lane < nb) ? bsum[lane] : 0;
    int own = v;
    for (int d = 1; d < 64; d <<= 1) {
        int u = __shfl_up(v, d, 64);
        if (lane >= d) v += u;
    }
    if (lane < nb) bsum[lane] = v - own;
}

// also seeds cursor[] = off[] when cursor != nullptr
__global__ __launch_bounds__(256) void k2c_add_prefix(
    int* __restrict__ off, const int* __restrict__ bsum,
    int* __restrict__ cursor, int S)
{
    int i = blockIdx.x * 256 + threadIdx.x;
    if (i >= S) return;
    int o = off[i] + bsum[i / SCAN_BLK];
    off[i] = o;
    if (cursor) cursor[i] = o;
}

// ---------- kA2: fused gather + MLP, scatter DIRECTLY into sp order ----------
__global__ __launch_bounds__(256) void kA2_mlp_scatter(
    const float* __restrict__ voxel_feats,
    const float* __restrict__ xyz,
    const float* __restrict__ W1, const float* __restrict__ b1,
    const float* __restrict__ gamma, const float* __restrict__ beta,
    const float* __restrict__ W2, const float* __restrict__ b2,
    const int* __restrict__ p2v, const int* __restrict__ sp_ids,
    int* __restrict__ cursor,
    uint4* __restrict__ y_s,            // [N*4] : 64 B bf16 row, sp-ordered
    uint4* __restrict__ xyzp,           // [N]   : {x,y,z,p}, sp-ordered
    int n)
{
    int p = blockIdx.x * 256 + threadIdx.x;
    if (p >= n) return;

    // independent work first: atomic claims the FINAL slot (latency hides
    // under the gather + MLP below)
    int sp = sp_ids[p];
    int j = atomicAdd(&cursor[sp], 1);

    // issue voxel gather early; result consumed only at the very end
    int v = p2v[p];
    const float4* vrow = (const float4*)(voxel_feats + (size_t)v * C);
    float4 g0 = vrow[0], g1 = vrow[1], g2 = vrow[2], g3 = vrow[3];
    float4 g4 = vrow[4], g5 = vrow[5], g6 = vrow[6], g7 = vrow[7];

    float x0 = xyz[3 * p + 0];
    float x1 = xyz[3 * p + 1];
    float x2 = xyz[3 * p + 2];

    // Linear(3,32)
    float h[C];
    #pragma unroll
    for (int c = 0; c < C; ++c)
        h[c] = fmaf(x0, W1[c], fmaf(x1, W1[C + c], fmaf(x2, W1[2 * C + c], b1[c])));

    // LayerNorm(32)
    float s = 0.f, s2 = 0.f;
    #pragma unroll
    for (int c = 0; c < C; ++c) { s += h[c]; s2 += h[c] * h[c]; }
    float mu   = s * (1.0f / C);
    float var  = fmaf(-mu, mu, s2 * (1.0f / C));
    float rstd = rsqrtf(var + LN_EPS);
    #pragma unroll
    for (int c = 0; c < C; ++c)
        h[c] = fmaxf(fmaf((h[c] - mu) * rstd, gamma[c], beta[c]), 0.0f);

    // acc = b2 + h @ W2
    float acc[C];
    #pragma unroll
    for (int c = 0; c < C; ++c) acc[c] = b2[c];
    #pragma unroll
    for (int k = 0; k < C; ++k) {
        float rk = h[k];
        #pragma unroll
        for (int c = 0; c < C; ++c)
            acc[c] = fmaf(rk, W2[k * C + c], acc[c]);
    }

    // add gathered voxel row
    float gf[C] = { g0.x,g0.y,g0.z,g0.w, g1.x,g1.y,g1.z,g1.w,
                    g2.x,g2.y,g2.z,g2.w, g3.x,g3.y,g3.z,g3.w,
                    g4.x,g4.y,g4.z,g4.w, g5.x,g5.y,g5.z,g5.w,
                    g6.x,g6.y,g6.z,g6.w, g7.x,g7.y,g7.z,g7.w };
    #pragma unroll
    for (int c = 0; c < C; ++c) acc[c] += gf[c];

    // pack bf16 and scatter 64 B at final sp-ordered position j
    uint4 y0, y1, y2, y3;
    y0.x = pack_bf16x2(acc[0],  acc[1]);  y0.y = pack_bf16x2(acc[2],  acc[3]);
    y0.z = pack_bf16x2(acc[4],  acc[5]);  y0.w = pack_bf16x2(acc[6],  acc[7]);
    y1.x = pack_bf16x2(acc[8],  acc[9]);  y1.y = pack_bf16x2(acc[10], acc[11]);
    y1.z = pack_bf16x2(acc[12], acc[13]); y1.w = pack_bf16x2(acc[14], acc[15]);
    y2.x = pack_bf16x2(acc[16], acc[17]); y2.y = pack_bf16x2(acc[18], acc[19]);
    y2.z = pack_bf16x2(acc[20], acc[21]); y2.w = pack_bf16x2(acc[22], acc[23]);
    y3.x = pack_bf16x2(acc[24], acc[25]); y3.y = pack_bf16x2(acc[26], acc[27]);
    y3.z = pack_bf16x2(acc[28], acc[29]); y3.w = pack_bf16x2(acc[30], acc[31]);
    uint4* dst = y_s + (size_t)j * 4;
    dst[0] = y0; dst[1] = y1; dst[2] = y2; dst[3] = y3;

    xyzp[j] = make_uint4(__float_as_uint(x0), __float_as_uint(x1),
                         __float_as_uint(x2), (unsigned)p);
}

// ---------- kB3: fully SEQUENTIAL streaming reduce ---------------------------
__global__ __launch_bounds__(256) void kB3_stream_reduce(
    const uint4* __restrict__ y_s,          // [N*4] sp-ordered
    const uint4* __restrict__ xyzp,         // [N]   sp-ordered
    const int* __restrict__ off, const int* __restrict__ count,
    float* __restrict__ out_x, float* __restrict__ out_xyz, int S)
{
    int gt  = blockIdx.x * 256 + threadIdx.x;
    int sp  = gt >> 3;
    int sub = gt & 7;
    if (sp >= S) return;

    int n    = count[sp];
    int base = off[sp];

    float acc[C];
    #pragma unroll
    for (int c = 0; c < C; ++c) acc[c] = 0.f;
    float ax = 0.f, ay = 0.f, az = 0.f;

    int i = sub;
    // 2-way unrolled: two sequential records in flight
    for (; i + P < n; i += 2 * P) {
        int j0 = base + i, j1 = base + i + P;
        const uint4* q0 = y_s + (size_t)j0 * 4;
        const uint4* q1 = y_s + (size_t)j1 * 4;
        uint4 a0 = q0[0], b0 = q0[1], c0 = q0[2], d0 = q0[3];
        uint4 a1 = q1[0], b1_ = q1[1], c1 = q1[2], d1 = q1[3];
        uint4 r0 = xyzp[j0];
        uint4 r1 = xyzp[j1];
        ax += __uint_as_float(r0.x) + __uint_as_float(r1.x);
        ay += __uint_as_float(r0.y) + __uint_as_float(r1.y);
        az += __uint_as_float(r0.z) + __uint_as_float(r1.z);
        unsigned w0[16] = { a0.x,a0.y,a0.z,a0.w, b0.x,b0.y,b0.z,b0.w,
                            c0.x,c0.y,c0.z,c0.w, d0.x,d0.y,d0.z,d0.w };
        unsigned w1[16] = { a1.x,a1.y,a1.z,a1.w, b1_.x,b1_.y,b1_.z,b1_.w,
                            c1.x,c1.y,c1.z,c1.w, d1.x,d1.y,d1.z,d1.w };
        #pragma unroll
        for (int q = 0; q < 16; ++q) {
            acc[2 * q + 0] += __uint_as_float(w0[q] << 16) + __uint_as_float(w1[q] << 16);
            acc[2 * q + 1] += __uint_as_float(w0[q] & 0xFFFF0000u) + __uint_as_float(w1[q] & 0xFFFF0000u);
        }
    }
    if (i < n) {
        int j0 = base + i;
        const uint4* q0 = y_s + (size_t)j0 * 4;
        uint4 a0 = q0[0], b0 = q0[1], c0 = q0[2], d0 = q0[3];
        uint4 r0 = xyzp[j0];
        ax += __uint_as_float(r0.x);
        ay += __uint_as_float(r0.y);
        az += __uint_as_float(r0.z);
        unsigned w0[16] = { a0.x,a0.y,a0.z,a0.w, b0.x,b0.y,b0.z,b0.w,
                            c0.x,c0.y,c0.z,c0.w, d0.x,d0.y,d0.z,d0.w };
        #pragma unroll
        for (int q = 0; q < 16; ++q) {
            acc[2 * q + 0] += __uint_as_float(w0[q] << 16);
            acc[2 * q + 1] += __uint_as_float(w0[q] & 0xFFFF0000u);
        }
    }

    #pragma unroll
    for (int c = 0; c < C; ++c) {
        acc[c] += __shfl_xor(acc[c], 1);
        acc[c] += __shfl_xor(acc[c], 2);
        acc[c] += __shfl_xor(acc[c], 4);
    }
    ax += __shfl_xor(ax, 1); ax += __shfl_xor(ax, 2); ax += __shfl_xor(ax, 4);
    ay += __shfl_xor(ay, 1); ay += __shfl_xor(ay, 2); ay += __shfl_xor(ay, 4);
    az += __shfl_xor(az, 1); az += __shfl_xor(az, 2); az += __shfl_xor(az, 4);

    if (sub == 0) {
        float inv = 1.0f / fmaxf((float)n, 1.0f);
        float4* o4 = (float4*)(out_x + (size_t)sp * C);
        #pragma unroll
        for (int q = 0; q < 8; ++q) {
            float4 f;
            f.x = acc[4 * q + 0] * inv;
            f.y = acc[4 * q + 1] * inv;
            f.z = acc[4 * q + 2] * inv;
            f.w = acc[4 * q + 3] * inv;
            o4[q] = f;
        }
        out_xyz[3 * sp + 0] = ax * inv;
        out_xyz[3 * sp + 1] = ay * inv;
        out_xyz[3 * sp + 2] = az * inv;
    }
}

// ---------- fallback tier (old R5 path, kept for small workspaces) -----------
__global__ __launch_bounds__(256) void kA1_rank_mlp_seq(
    const float* __restrict__ voxel_feats,
    const float* __restrict__ xyz,
    const float* __restrict__ W1, const float* __restrict__ b1,
    const float* __restrict__ gamma, const float* __restrict__ beta,
    const float* __restrict__ W2, const float* __restrict__ b2,
    const int* __restrict__ p2v, const int* __restrict__ sp_ids,
    int* __restrict__ count, int* __restrict__ rank,
    uint4* __restrict__ y_s, int n)
{
    int p = blockIdx.x * 256 + threadIdx.x;
    if (p >= n) return;
    int sp = sp_ids[p];
    rank[p] = atomicAdd(&count[sp], 1);
    int v = p2v[p];
    const float4* vrow = (const float4*)(voxel_feats + (size_t)v * C);
    float4 g0 = vrow[0], g1 = vrow[1], g2 = vrow[2], g3 = vrow[3];
    float4 g4 = vrow[4], g5 = vrow[5], g6 = vrow[6], g7 = vrow[7];
    float x0 = xyz[3 * p + 0], x1 = xyz[3 * p + 1], x2 = xyz[3 * p + 2];
    float h[C];
    #pragma unroll
    for (int c = 0; c < C; ++c)
        h[c] = fmaf(x0, W1[c], fmaf(x1, W1[C + c], fmaf(x2, W1[2 * C + c], b1[c])));
    float s = 0.f, s2 = 0.f;
    #pragma unroll
    for (int c = 0; c < C; ++c) { s += h[c]; s2 += h[c] * h[c]; }
    float mu = s * (1.0f / C);
    float var = fmaf(-mu, mu, s2 * (1.0f / C));
    float rstd = rsqrtf(var + LN_EPS);
    #pragma unroll
    for (int c = 0; c < C; ++c)
        h[c] = fmaxf(fmaf((h[c] - mu) * rstd, gamma[c], beta[c]), 0.0f);
    float acc[C];
    #pragma unroll
    for (int c = 0; c < C; ++c) acc[c] = b2[c];
    #pragma unroll
    for (int k = 0; k < C; ++k) {
        float rk = h[k];
        #pragma unroll
        for (int c = 0; c < C; ++c) acc[c] = fmaf(rk, W2[k * C + c], acc[c]);
    }
    float gf[C] = { g0.x,g0.y,g0.z,g0.w, g1.x,g1.y,g1.z,g1.w,
                    g2.x,g2.y,g2.z,g2.w, g3.x,g3.y,g3.z,g3.w,
                    g4.x,g4.y,g4.z,g4.w, g5.x,g5.y,g5.z,g5.w,
                    g6.x,g6.y,g6.z,g6.w, g7.x,g7.y,g7.z,g7.w };
    #pragma unroll
    for (int c = 0; c < C; ++c) acc[c] += gf[c];
    uint4 y0, y1, y2, y3;
    y0.x = pack_bf16x2(acc[0],  acc[1]);  y0.y = pack_bf16x2(acc[2],  acc[3]);
    y0.z = pack_bf16x2(acc[4],  acc[5]);  y0.w = pack_bf16x2(acc[6],  acc[7]);
    y1.x = pack_bf16x2(acc[8],  acc[9]);  y1.y = pack_bf16x2(acc[10], acc[11]);
    y1.z = pack_bf16x2(acc[12], acc[13]); y1.w = pack_bf16x2(acc[14], acc[15]);
    y2.x = pack_bf16x2(acc[16], acc[17]); y2.y = pack_bf16x2(acc[18], acc[19]);
    y2.z = pack_bf16x2(acc[20], acc[21]); y2.w = pack_bf16x2(acc[22], acc[23]);
    y3.x = pack_bf16x2(acc[24], acc[25]); y3.y = pack_bf16x2(acc[26], acc[27]);
    y3.z = pack_bf16x2(acc[28], acc[29]); y3.w = pack_bf16x2(acc[30], acc[31]);
    uint4* dst = y_s + (size_t)p * 4;
    dst[0] = y0; dst[1] = y1; dst[2] = y2; dst[3] = y3;
}

__global__ __launch_bounds__(256) void k3_reorder(
    const int* __restrict__ sp_ids, const int* __restrict__ rank,
    const int* __restrict__ off, int* __restrict__ order, int n)
{
    int p = blockIdx.x * 256 + threadIdx.x;
    if (p >= n) return;
    order[off[sp_ids[p]] + rank[p]] = p;
}

__global__ __launch_bounds__(256) void kB_gather_reduce(
    const uint4* __restrict__ y_s, const float* __restrict__ xyz,
    const int* __restrict__ order,
    const int* __restrict__ off, const int* __restrict__ count,
    float* __restrict__ out_x, float* __restrict__ out_xyz, int S)
{
    int gt = blockIdx.x * 256 + threadIdx.x;
    int sp = gt >> 3, sub = gt & 7;
    if (sp >= S) return;
    int n = count[sp], base = off[sp];
    float acc[C];
    #pragma unroll
    for (int c = 0; c < C; ++c) acc[c] = 0.f;
    float ax = 0.f, ay = 0.f, az = 0.f;
    for (int i = sub; i < n; i += P) {
        int o = order[base + i];
        const uint4* r = y_s + (size_t)o * 4;
        uint4 a = r[0], b = r[1], c4 = r[2], d = r[3];
        const float* xp = xyz + 3 * (size_t)o;
        ax += xp[0]; ay += xp[1]; az += xp[2];
        unsigned w[16] = { a.x,a.y,a.z,a.w, b.x,b.y,b.z,b.w,
                           c4.x,c4.y,c4.z,c4.w, d.x,d.y,d.z,d.w };
        #pragma unroll
        for (int q = 0; q < 16; ++q) {
            acc[2 * q + 0] += __uint_as_float(w[q] << 16);
            acc[2 * q + 1] += __uint_as_float(w[q] & 0xFFFF0000u);
        }
    }
    #pragma unroll
    for (int c = 0; c < C; ++c) {
        acc[c] += __shfl_xor(acc[c], 1);
        acc[c] += __shfl_xor(acc[c], 2);
        acc[c] += __shfl_xor(acc[c], 4);
    }
    ax += __shfl_xor(ax, 1); ax += __shfl_xor(ax, 2); ax += __shfl_xor(ax, 4);
    ay += __shfl_xor(ay, 1); ay += __shfl_xor(ay, 2); ay += __shfl_xor(ay, 4);
    az += __shfl_xor(az, 1); az += __shfl_xor(az, 2); az += __shfl_xor(az, 4);
    if (sub == 0) {
        float inv = 1.0f / fmaxf((float)n, 1.0f);
        float4* o4 = (float4*)(out_x + (size_t)sp * C);
        #pragma unroll
        for (int q = 0; q < 8; ++q) {
            float4 f;
            f.x = acc[4 * q + 0] * inv; f.y = acc[4 * q + 1] * inv;
            f.z = acc[4 * q + 2] * inv; f.w = acc[4 * q + 3] * inv;
            o4[q] = f;
        }
        out_xyz[3 * sp + 0] = ax * inv;
        out_xyz[3 * sp + 1] = ay * inv;
        out_xyz[3 * sp + 2] = az * inv;
    }
}

extern "C" void kernel_launch(void* const* d_in, const int* in_sizes, int n_in,
                              void* d_out, int out_size, void* d_ws, size_t ws_size,
                              hipStream_t stream)
{
    const float* voxel_feats = (const float*)d_in[0];
    const float* xyz         = (const float*)d_in[1];
    const float* W1          = (const float*)d_in[2];
    const float* b1          = (const float*)d_in[3];
    const float* gamma       = (const float*)d_in[4];
    const float* beta        = (const float*)d_in[5];
    const float* W2          = (const float*)d_in[6];
    const float* b2          = (const float*)d_in[7];
    const int*   p2v         = (const int*)d_in[8];
    const int*   sp_ids      = (const int*)d_in[9];

    const int n_pts = in_sizes[8];
    const int S     = out_size / 35;

    float* out_x   = (float*)d_out;
    float* out_xyz = out_x + (size_t)S * C;

    int blk = 256;
    int gpts = (n_pts + blk - 1) / blk;
    int nb = (S + SCAN_BLK - 1) / SCAN_BLK;
    int n_thr = S * P;

    // primary layout (ints): count[S] | off[S] | bsum[64] | cursor[S]
    int* count  = (int*)d_ws;
    int* off    = count + S;
    int* bsum   = off + S;
    int* cursor = bsum + 64;

    size_t head_b = ((size_t)(3 * S) + 64) * sizeof(int);
    head_b = (head_b + 255) & ~(size_t)255;
    size_t xyzp_b = (size_t)n_pts * 16;
    size_t y_b    = (size_t)n_pts * 64;

    hipMemsetAsync(count, 0, (size_t)S * sizeof(int), stream);

    if (ws_size >= head_b + xyzp_b + y_b) {
        uint4* xyzp = (uint4*)((char*)d_ws + head_b);
        uint4* y_s  = (uint4*)((char*)d_ws + head_b + xyzp_b);

        // 1. histogram (cheap) -> 2. scan (cheap, also seeds cursor)
        k0_hist<<<gpts, blk, 0, stream>>>(sp_ids, count, n_pts);
        k2a_scan_block<<<nb, SCAN_BLK, 0, stream>>>(count, off, bsum, S);
        k2b_scan_bsums<<<1, 64, 0, stream>>>(bsum, nb);
        k2c_add_prefix<<<(S + blk - 1) / blk, blk, 0, stream>>>(off, bsum, cursor, S);
        // 3. MLP + gather, scatter directly into sp order (writes don't stall)
        kA2_mlp_scatter<<<gpts, blk, 0, stream>>>(
            voxel_feats, xyz, W1, b1, gamma, beta, W2, b2,
            p2v, sp_ids, cursor, y_s, xyzp, n_pts);
        // 4. fully sequential streaming reduce
        kB3_stream_reduce<<<(n_thr + blk - 1) / blk, blk, 0, stream>>>(
            y_s, xyzp, off, count, out_x, out_xyz, S);
    } else {
        // R5 layout: count[S] | off[S] | bsum[64] | rank[N] | order[N] | y_s
        int* rank  = bsum + 64;
        int* order = rank + n_pts;
        size_t head5_b = ((size_t)2 * S + 64 + (size_t)2 * n_pts) * sizeof(int);
        head5_b = (head5_b + 255) & ~(size_t)255;
        uint4* y_s = (uint4*)((char*)d_ws + head5_b);

        kA1_rank_mlp_seq<<<gpts, blk, 0, stream>>>(
            voxel_feats, xyz, W1, b1, gamma, beta, W2, b2,
            p2v, sp_ids, count, rank, y_s, n_pts);
        k2a_scan_block<<<nb, SCAN_BLK, 0, stream>>>(count, off, bsum, S);
        k2b_scan_bsums<<<1, 64, 0, stream>>>(bsum, nb);
        k2c_add_prefix<<<(S + blk - 1) / blk, blk, 0, stream>>>(off, bsum, (int*)nullptr, S);
        k3_reorder<<<gpts, blk, 0, stream>>>(sp_ids, rank, off, order, n_pts);
        kB_gather_reduce<<<(n_thr + blk - 1) / blk, blk, 0, stream>>>(
            y_s, xyz, order, off, count, out_x, out_xyz, S);
    }
}